// Round 10
// baseline (375.825 us; speedup 1.0000x reference)
//
#include <hip/hip_runtime.h>
#include <hip/hip_bf16.h>
#include <math.h>

// Problem constants (HC2MMoE)
#define B_    16384
#define IN_   1024
#define E_    6
#define D_    20
#define EH1_  256
#define EH2_  128
#define EO_   10
#define GH_   64
#define TH_   64

typedef short  s16x8  __attribute__((ext_vector_type(8)));   // 8 bf16 = 4 VGPRs
typedef float  f32x4  __attribute__((ext_vector_type(4)));
typedef float  f32x16 __attribute__((ext_vector_type(16)));

__device__ inline ushort f2bf(float f) {   // RNE fp32 -> bf16 bits
    union { float f; uint32_t u; } v; v.f = f;
    return (ushort)((v.u + 0x7fffu + ((v.u >> 16) & 1u)) >> 16);
}

#define GLOBAL_LDS16(g, l)                                                     \
    __builtin_amdgcn_global_load_lds(                                          \
        (const __attribute__((address_space(1))) void*)(g),                    \
        (__attribute__((address_space(3))) void*)(l), 16, 0, 0)

// ---------------------------------------------------------------------------
// Prep: fused x-convert + 3 weight transposes (flat grid, uniform branch)
// ---------------------------------------------------------------------------
#define CVT_BLKS  (B_ * IN_ / 4 / 256)                       // 16384
#define WT1_TILES ((EH1_ / 32) * (IN_ / 32) * E_)            // 1536
#define WT2_TILES ((EH2_ / 32) * (EH1_ / 32) * E_)           // 192
#define WTG_TILES ((GH_ / 32) * (IN_ / 32) * D_)             // 1280
#define PREP_BLKS (CVT_BLKS + WT1_TILES + WT2_TILES + WTG_TILES)

__global__ __launch_bounds__(256) void k_prep(
        const float* __restrict__ x, ushort* __restrict__ xb,
        const float* __restrict__ Ew1, ushort* __restrict__ W1t,
        const float* __restrict__ Ew2, ushort* __restrict__ W2t,
        const float* __restrict__ Gw1, ushort* __restrict__ G1t) {
    __shared__ float tile[32][33];
    int bid = blockIdx.x;
    const int t = threadIdx.x;

    if (bid < CVT_BLKS) {
        int i = bid * 256 + t;
        float4 v = ((const float4*)x)[i];
        ushort4 o;
        o.x = f2bf(v.x); o.y = f2bf(v.y); o.z = f2bf(v.z); o.w = f2bf(v.w);
        ((ushort4*)xb)[i] = o;
        return;
    }
    bid -= CVT_BLKS;

    const float* W; ushort* Wt; int K, N, z, ky, nx;
    if (bid < WT1_TILES) {
        W = Ew1; Wt = W1t; K = IN_; N = EH1_;
        z = bid / (8 * 32); int r = bid % (8 * 32); ky = r / 8; nx = r % 8;
    } else if (bid < WT1_TILES + WT2_TILES) {
        bid -= WT1_TILES;
        W = Ew2; Wt = W2t; K = EH1_; N = EH2_;
        z = bid / (4 * 8); int r = bid % (4 * 8); ky = r / 4; nx = r % 4;
    } else {
        bid -= WT1_TILES + WT2_TILES;
        W = Gw1; Wt = G1t; K = IN_; N = GH_;
        z = bid / (2 * 32); int r = bid % (2 * 32); ky = r / 2; nx = r % 2;
    }
    const int n0 = nx * 32, k0 = ky * 32;
    const float* We = W + (size_t)z * K * N;
    ushort* Wte = Wt + (size_t)z * K * N;
    const int lx = t & 31, ly = t >> 5;
    #pragma unroll
    for (int r = 0; r < 4; ++r)
        tile[ly + r * 8][lx] = We[(size_t)(k0 + ly + r * 8) * N + n0 + lx];
    __syncthreads();
    #pragma unroll
    for (int r = 0; r < 4; ++r)
        Wte[(size_t)(n0 + ly + r * 8) * K + k0 + lx] = f2bf(tile[lx][ly + r * 8]);
}

// ---------------------------------------------------------------------------
// Fused histogram + prefix (single block, LDS atomics)
// ---------------------------------------------------------------------------
__global__ __launch_bounds__(256) void k_prefix2(
        const int* __restrict__ dom, int* __restrict__ hist,
        int* __restrict__ baseA, int* __restrict__ cursor) {
    __shared__ int h[D_];
    const int t = threadIdx.x;
    if (t < D_) h[t] = 0;
    __syncthreads();
    for (int i = t; i < B_; i += 256) atomicAdd(&h[dom[i]], 1);
    __syncthreads();
    if (t == 0) {
        int s = 0;
        for (int i = 0; i < D_; ++i) {
            baseA[i] = s; cursor[i] = s; hist[i] = h[i]; s += h[i];
        }
    }
}

__global__ void k_scatter(const int* __restrict__ dom, int* __restrict__ cursor,
                          int* __restrict__ perm) {
    int g = blockIdx.x * blockDim.x + threadIdx.x;
    if (g < B_) {
        int pos = atomicAdd(&cursor[dom[g]], 1);
        perm[pos] = g;
    }
}

#define GBK 32
#define H2P 136

// ---------------------------------------------------------------------------
// bf16 MFMA GEMM, 32x32x16, 256x128 tile, BK=32, R8 staging (coalesced
// global: 4 lanes cover one row's 64B window) + XOR swizzle.
// Per K-window per wave: 16 MFMA vs 12 ds_read_b128 vs 6 staging calls
// (R8 was 8:8:4) -> 2x MFMA per barrier drain.
// A-frag: m=lane&31, k=(lane>>5)*8+j.  C/D: col=lane&31,
// row=(reg&3)+8*(reg>>2)+4*(lane>>5)  [HW-verified m74/m101].
// ---------------------------------------------------------------------------
__global__ __launch_bounds__(256) void k_mfma_gemm(
        const ushort* __restrict__ A, size_t aStride,
        const ushort* __restrict__ Wt, const float* __restrict__ Bias,
        ushort* __restrict__ C, int M, int N, int K, int eBase) {
    __shared__ __attribute__((aligned(16))) ushort As[256 * GBK]; // 16 KB
    __shared__ __attribute__((aligned(16))) ushort Bs[128 * GBK]; //  8 KB

    const int z = blockIdx.z;
    const int eAbs = eBase + z;
    const ushort* Ae = A + (size_t)z * aStride;
    const ushort* We = Wt + (size_t)eAbs * (size_t)N * K;
    const float* BiasE = Bias + (size_t)eAbs * N;
    ushort* Ce = C + (size_t)z * (size_t)M * N;

    const int m0 = blockIdx.y * 256;
    const int n0 = blockIdx.x * 128;
    const int t = threadIdx.x;
    const int wave = t >> 6;
    const int lane = t & 63;

    // staging: lane -> (row-in-16 = lane>>2, chunk = lane&3); swizzled k-off
    // is call-invariant since chunk-group base rows are multiples of 16.
    const int srow = lane >> 2;                    // 0..15 within a 16-row group
    const int sw   = ((lane & 3) ^ ((lane >> 3) & 3)) * 8;

    const int l32  = lane & 31;
    const int ksel = lane >> 5;
    const int rw = (wave & 1) * 128;   // row half (of 256)
    const int cw = (wave >> 1) * 64;   // col half (of 128)

    f32x16 acc[4][2] = {};

    for (int k0 = 0; k0 < K; k0 += GBK) {
        // A: wave stages 4 x 16-row groups (rows wave*64 .. wave*64+63)
        #pragma unroll
        for (int u = 0; u < 4; ++u) {
            const int qa = wave * 4 + u;
            GLOBAL_LDS16(Ae + (size_t)(m0 + qa * 16 + srow) * K + k0 + sw,
                         As + qa * 512);
        }
        // B: wave stages 2 x 16-row groups (cols wave*32 .. wave*32+31)
        #pragma unroll
        for (int v = 0; v < 2; ++v) {
            const int qb = wave * 2 + v;
            GLOBAL_LDS16(We + (size_t)(n0 + qb * 16 + srow) * K + k0 + sw,
                         Bs + qb * 512);
        }
        __syncthreads();

        #pragma unroll
        for (int h = 0; h < 2; ++h) {           // two K=16 halves per window
            const int cb = h * 2 + ksel;
            s16x8 af[4], bf[2];
            #pragma unroll
            for (int i = 0; i < 4; ++i) {
                int row = rw + 32 * i + l32;
                af[i] = *(const s16x8*)&As[row * GBK +
                                           ((cb ^ ((row >> 1) & 3)) * 8)];
            }
            #pragma unroll
            for (int j = 0; j < 2; ++j) {
                int col = cw + 32 * j + l32;
                bf[j] = *(const s16x8*)&Bs[col * GBK +
                                           ((cb ^ ((col >> 1) & 3)) * 8)];
            }
            #pragma unroll
            for (int i = 0; i < 4; ++i)
                #pragma unroll
                for (int j = 0; j < 2; ++j)
                    acc[i][j] = __builtin_amdgcn_mfma_f32_32x32x16_bf16(
                        af[i], bf[j], acc[i][j], 0, 0, 0);
        }
        __syncthreads();
    }

    // epilogue: direct stores, 32x32 C/D layout
    float bi[2];
    #pragma unroll
    for (int j = 0; j < 2; ++j) bi[j] = BiasE[n0 + cw + 32 * j + l32];

    #pragma unroll
    for (int i = 0; i < 4; ++i) {
        #pragma unroll
        for (int reg = 0; reg < 16; ++reg) {
            int rowin = (reg & 3) + 8 * (reg >> 2) + 4 * ksel;
            ushort* crow = Ce + (size_t)(m0 + rw + 32 * i + rowin) * N;
            #pragma unroll
            for (int j = 0; j < 2; ++j) {
                float v = fmaxf(acc[i][j][reg] + bi[j], 0.f);
                crow[n0 + cw + 32 * j + l32] = f2bf(v);
            }
        }
    }
}

// ---------------------------------------------------------------------------
// Fused expert L2+L3 (unchanged, 16x16x32 + XOR swizzle verified R5):
// h2 = relu(h1 . W2^T + Eb2), then eo = h2 . Ew3 + Eb3 in-block.
// ---------------------------------------------------------------------------
__global__ __launch_bounds__(256) void k_l2eo(
        const ushort* __restrict__ h1, const ushort* __restrict__ W2t,
        const float* __restrict__ Eb2, const float* __restrict__ Ew3,
        const float* __restrict__ Eb3, float* __restrict__ eo, int eBase) {
    __shared__ __attribute__((aligned(16))) ushort smem[17408 + 16 * H2P];
    ushort* As = smem;            // 128*32 elems (main loop)
    ushort* Bs = smem + 4096;     // 128*32 elems (main loop)

    const int z = blockIdx.y;
    const int eAbs = eBase + z;
    const ushort* Ae = h1 + (size_t)z * B_ * EH1_;
    const ushort* We = W2t + (size_t)eAbs * EH2_ * EH1_;   // [N=128][K=256]

    const int m0 = blockIdx.x * 128;
    const int t = threadIdx.x;
    const int wave = t >> 6;
    const int lane = t & 63;

    const int q0 = wave * 2, q1 = q0 + 1;
    const int sr0 = q0 * 16 + (lane >> 2);
    const int sr1 = sr0 + 16;
    const int sw  = ((lane & 3) ^ ((sr0 >> 1) & 3)) * 8;

    const int quad = lane >> 4;
    const int l16  = lane & 15;
    const int qsw  = (quad ^ ((l16 >> 1) & 3)) * 8;
    const int rw = (wave & 1) * 64;
    const int cw = (wave >> 1) * 64;

    f32x4 acc[4][4] = {};

    for (int k0 = 0; k0 < EH1_; k0 += GBK) {
        GLOBAL_LDS16(Ae + (size_t)(m0 + sr0) * EH1_ + k0 + sw, As + q0 * 512);
        GLOBAL_LDS16(Ae + (size_t)(m0 + sr1) * EH1_ + k0 + sw, As + q1 * 512);
        GLOBAL_LDS16(We + (size_t)sr0 * EH1_ + k0 + sw, Bs + q0 * 512);
        GLOBAL_LDS16(We + (size_t)sr1 * EH1_ + k0 + sw, Bs + q1 * 512);
        __syncthreads();

        s16x8 af[4], bf[4];
        #pragma unroll
        for (int i = 0; i < 4; ++i)
            af[i] = *(const s16x8*)&As[(rw + 16 * i + l16) * GBK + qsw];
        #pragma unroll
        for (int j = 0; j < 4; ++j)
            bf[j] = *(const s16x8*)&Bs[(cw + 16 * j + l16) * GBK + qsw];
        #pragma unroll
        for (int i = 0; i < 4; ++i)
            #pragma unroll
            for (int j = 0; j < 4; ++j)
                acc[i][j] = __builtin_amdgcn_mfma_f32_16x16x32_bf16(
                    af[i], bf[j], acc[i][j], 0, 0, 0);
        __syncthreads();
    }

    // epilogue: h2 tile (bias+relu, bf16) -> LDS in A-readable layout
    ushort* h2L = smem;             // [128][H2P]
    ushort* E3t = smem + 128 * H2P; // [16][H2P]  (cols >= EO_ zero)

    float bi[4];
    #pragma unroll
    for (int j = 0; j < 4; ++j) bi[j] = Eb2[eAbs * EH2_ + cw + 16 * j + l16];

    #pragma unroll
    for (int i = 0; i < 4; ++i)
        #pragma unroll
        for (int r = 0; r < 4; ++r) {
            int row = rw + 16 * i + quad * 4 + r;
            #pragma unroll
            for (int j = 0; j < 4; ++j)
                h2L[row * H2P + cw + 16 * j + l16] =
                    f2bf(fmaxf(acc[i][j][r] + bi[j], 0.f));
        }

    for (int i = t; i < 16 * 128; i += 256) {
        int col = i >> 7, k = i & 127;
        float v = (col < EO_) ? Ew3[(size_t)eAbs * EH2_ * EO_ + k * EO_ + col] : 0.f;
        E3t[col * H2P + k] = f2bf(v);
    }
    __syncthreads();

    #pragma unroll
    for (int gi = 0; gi < 2; ++gi) {
        int g = wave * 2 + gi;
        f32x4 acc2 = {};
        #pragma unroll
        for (int kc = 0; kc < 4; ++kc) {
            s16x8 a = *(const s16x8*)&h2L[(g * 16 + l16) * H2P + kc * 32 + quad * 8];
            s16x8 b = *(const s16x8*)&E3t[l16 * H2P + kc * 32 + quad * 8];
            acc2 = __builtin_amdgcn_mfma_f32_16x16x32_bf16(a, b, acc2, 0, 0, 0);
        }
        if (l16 < EO_) {
            float b3 = Eb3[eAbs * EO_ + l16];
            #pragma unroll
            for (int r = 0; r < 4; ++r) {
                int row = m0 + g * 16 + quad * 4 + r;
                eo[(size_t)row * (E_ * EO_) + eAbs * EO_ + l16] = acc2[r] + b3;
            }
        }
    }
}

// ---------------------------------------------------------------------------
// Gate (MFMA, fused): per (domain, 64-row tile) block, with bank swizzle.
// ---------------------------------------------------------------------------
__global__ __launch_bounds__(256) void k_gate2(
        const ushort* __restrict__ xb, const ushort* __restrict__ Gw1t,
        const float* __restrict__ Gb1, const float* __restrict__ Gw2,
        const float* __restrict__ Gb2, const int* __restrict__ perm,
        const int* __restrict__ baseA, const int* __restrict__ cntA,
        float* __restrict__ gate) {
    const int d = blockIdx.y;
    const int cnt = cntA[d];
    const int start = blockIdx.x * 64;
    if (start >= cnt) return;
    const int base = baseA[d];

    __shared__ __attribute__((aligned(16))) ushort As[64 * 32];
    __shared__ __attribute__((aligned(16))) ushort Bs[64 * 32];
    __shared__ int    ridx[64];
    __shared__ float  gh[64][GH_ + 1];
    __shared__ float  w2s[GH_ * E_];
    __shared__ float  b2s[E_];
    __shared__ float  lg[64][E_];

    const int t = threadIdx.x;
    const int wave = t >> 6;
    const int lane = t & 63;
    const int quad = lane >> 4;
    const int l16  = lane & 15;
    const int qsw  = (quad ^ ((l16 >> 1) & 3)) * 8;

    if (t < 64) {
        int p = start + t;
        ridx[t] = (p < cnt) ? perm[base + p] : perm[base];  // clamp OOB
    }
    for (int i = t; i < GH_ * E_; i += 256) w2s[i] = Gw2[(size_t)d * GH_ * E_ + i];
    if (t < E_) b2s[t] = Gb2[d * E_ + t];
    __syncthreads();

    const int srow = t >> 2;
    const int sw   = ((t & 3) ^ ((srow >> 1) & 3)) * 8;
    const int myRow = ridx[srow];
    const ushort* aRow = xb + (size_t)myRow * IN_ + sw;
    const ushort* bRow = Gw1t + (size_t)d * GH_ * IN_ + (size_t)srow * IN_ + sw;

    f32x4 acc[4] = {};
    for (int k0 = 0; k0 < IN_; k0 += 32) {
        GLOBAL_LDS16(aRow + k0, As + wave * 512);
        GLOBAL_LDS16(bRow + k0, Bs + wave * 512);
        __syncthreads();

        s16x8 bf = *(const s16x8*)&Bs[(wave * 16 + l16) * 32 + qsw];
        #pragma unroll
        for (int i = 0; i < 4; ++i) {
            s16x8 af = *(const s16x8*)&As[(16 * i + l16) * 32 + qsw];
            acc[i] = __builtin_amdgcn_mfma_f32_16x16x32_bf16(af, bf, acc[i], 0, 0, 0);
        }
        __syncthreads();
    }

    const int hcol = wave * 16 + l16;
    float hb = Gb1[d * GH_ + hcol];
    #pragma unroll
    for (int i = 0; i < 4; ++i)
        #pragma unroll
        for (int r = 0; r < 4; ++r)
            gh[16 * i + quad * 4 + r][hcol] = fmaxf(acc[i][r] + hb, 0.f);
    __syncthreads();

    // layer 2: 64 rows x 6 experts = 384 pairs, strided over 256 threads
    for (int p = t; p < 64 * E_; p += 256) {
        int row = p / E_, e = p - row * E_;
        float s = b2s[e];
        #pragma unroll 8
        for (int h = 0; h < GH_; ++h) s += gh[row][h] * w2s[h * E_ + e];
        lg[row][e] = s;
    }
    __syncthreads();

    if (t < 64 && start + t < cnt) {
        int b = ridx[t];
        float mx = lg[t][0];
        #pragma unroll
        for (int e = 1; e < E_; ++e) mx = fmaxf(mx, lg[t][e]);
        float ex[E_], sum = 0.f;
        #pragma unroll
        for (int e = 0; e < E_; ++e) { ex[e] = expf(lg[t][e] - mx); sum += ex[e]; }
        float inv = 1.f / sum;
        #pragma unroll
        for (int e = 0; e < E_; ++e) gate[(size_t)b * E_ + e] = ex[e] * inv;
    }
}

// ---------------------------------------------------------------------------
// Final: MMoE combine + avg + tower, one wave per sample
// ---------------------------------------------------------------------------
__global__ __launch_bounds__(256) void k_final(
        const float* __restrict__ eo, const float* __restrict__ gate,
        const int* __restrict__ dom,
        const float* __restrict__ Tw1, const float* __restrict__ Tb1,
        const float* __restrict__ Tw2, const float* __restrict__ Tb2,
        float* __restrict__ out) {
    const int wave = threadIdx.x >> 6;
    const int lane = threadIdx.x & 63;
    const int b = blockIdx.x * 4 + wave;
    const int d = dom[b];

    const float* eob = eo + (size_t)b * (E_ * EO_);
    float g[E_];
    #pragma unroll
    for (int e = 0; e < E_; ++e) g[e] = gate[(size_t)b * E_ + e];

    float mmoe[EO_], avg[EO_];
    #pragma unroll
    for (int o = 0; o < EO_; ++o) {
        float m = 0.f, a = 0.f;
        #pragma unroll
        for (int e = 0; e < E_; ++e) {
            float v = eob[e * EO_ + o];
            m += g[e] * v;
            a += v;
        }
        mmoe[o] = m;
        avg[o] = a * (1.0f / E_);
    }

    float acc = Tb1[d * TH_ + lane];
    #pragma unroll
    for (int o = 0; o < EO_; ++o)
        acc += mmoe[o] * Tw1[(size_t)d * EO_ * TH_ + o * TH_ + lane];
    acc = fmaxf(acc, 0.f);

    float s = acc * Tw2[d * TH_ + lane];
    #pragma unroll
    for (int off = 32; off >= 1; off >>= 1) s += __shfl_xor(s, off, 64);

    if (lane == 0)
        out[b] = 1.f / (1.f + expf(-(s + Tb2[d])));
    if (lane < EO_) {
        out[B_ + (size_t)b * EO_ + lane] = avg[lane];
        out[B_ + (size_t)B_ * EO_ + (size_t)b * EO_ + lane] = mmoe[lane];
    }
}

// ---------------------------------------------------------------------------
extern "C" void kernel_launch(void* const* d_in, const int* in_sizes, int n_in,
                              void* d_out, int out_size, void* d_ws, size_t ws_size,
                              hipStream_t stream) {
    const float* x   = (const float*)d_in[0];
    const int*   dom = (const int*)d_in[1];
    const float* Ew1 = (const float*)d_in[2];
    const float* Eb1 = (const float*)d_in[3];
    const float* Ew2 = (const float*)d_in[4];
    const float* Eb2 = (const float*)d_in[5];
    const float* Ew3 = (const float*)d_in[6];
    const float* Eb3 = (const float*)d_in[7];
    const float* Gw1 = (const float*)d_in[8];
    const float* Gb1 = (const float*)d_in[9];
    const float* Gw2 = (const float*)d_in[10];
    const float* Gb2 = (const float*)d_in[11];
    const float* Tw1 = (const float*)d_in[12];
    const float* Tb1 = (const float*)d_in[13];
    const float* Tw2 = (const float*)d_in[14];
    const float* Tb2 = (const float*)d_in[15];
    float* out = (float*)d_out;

    char* ws = (char*)d_ws;
    size_t off = 0;
    auto take = [&](size_t bytes) -> char* {
        char* p = ws + off;
        off = (off + bytes + 255) & ~(size_t)255;
        return p;
    };
    int*    hist    = (int*)take(D_ * 4);
    int*    baseA   = (int*)take(D_ * 4);
    int*    cursor  = (int*)take(D_ * 4);
    int*    perm    = (int*)take(B_ * 4);
    float*  gateBuf = (float*)take((size_t)B_ * E_ * 4);
    float*  eoBuf   = (float*)take((size_t)B_ * E_ * EO_ * 4);
    ushort* xb      = (ushort*)take((size_t)B_ * IN_ * 2);
    ushort* W1t     = (ushort*)take((size_t)E_ * IN_ * EH1_ * 2);
    ushort* W2t     = (ushort*)take((size_t)E_ * EH1_ * EH2_ * 2);
    ushort* G1t     = (ushort*)take((size_t)D_ * IN_ * GH_ * 2);
    size_t fixed = off;

    int G = 1;
    const int cands[4] = {6, 3, 2, 1};
    for (int ci = 0; ci < 4; ++ci) {
        size_t need = fixed + (size_t)cands[ci] * B_ * EH1_ * 2 + 1024;
        if (need <= ws_size) { G = cands[ci]; break; }
    }
    ushort* h1 = (ushort*)take((size_t)G * B_ * EH1_ * 2);

    // fused conversions (cvt + all weight transposes)
    k_prep<<<dim3(PREP_BLKS), dim3(256), 0, stream>>>(
        x, xb, Ew1, W1t, Ew2, W2t, Gw1, G1t);

    // domain bucketing (hist+prefix fused, then scatter)
    k_prefix2<<<dim3(1), dim3(256), 0, stream>>>(dom, hist, baseA, cursor);
    k_scatter<<<dim3(B_ / 256), dim3(256), 0, stream>>>(dom, cursor, perm);

    // gates (selected domain only, MFMA + fused softmax)
    k_gate2<<<dim3((B_ + 63) / 64, D_), dim3(256), 0, stream>>>(
        xb, G1t, Gb1, Gw2, Gb2, perm, baseA, hist, gateBuf);

    // experts: L1 MFMA gemm (32x32x16, 256x128 tile), then fused L2+L3
    for (int g0 = 0; g0 < E_; g0 += G) {
        k_mfma_gemm<<<dim3(EH1_ / 128, B_ / 256, G), dim3(256), 0, stream>>>(
            xb, (size_t)0, W1t, Eb1, h1, B_, EH1_, IN_, g0);
        k_l2eo<<<dim3(B_ / 128, G), dim3(256), 0, stream>>>(
            h1, W2t, Eb2, Ew3, Eb3, eoBuf, g0);
    }

    // combine + towers + outputs
    k_final<<<dim3(B_ / 4), dim3(256), 0, stream>>>(
        eoBuf, gateBuf, dom, Tw1, Tb1, Tw2, Tb2, out);
}

// Round 11
// 320.143 us; speedup vs baseline: 1.1739x; 1.1739x over previous
//
#include <hip/hip_runtime.h>
#include <hip/hip_bf16.h>
#include <math.h>

// Problem constants (HC2MMoE)
#define B_    16384
#define IN_   1024
#define E_    6
#define D_    20
#define EH1_  256
#define EH2_  128
#define EO_   10
#define GH_   64
#define TH_   64

typedef short  s16x8  __attribute__((ext_vector_type(8)));   // 8 bf16 = 4 VGPRs
typedef float  f32x4  __attribute__((ext_vector_type(4)));
typedef float  f32x16 __attribute__((ext_vector_type(16)));

__device__ inline ushort f2bf(float f) {   // RNE fp32 -> bf16 bits
    union { float f; uint32_t u; } v; v.f = f;
    return (ushort)((v.u + 0x7fffu + ((v.u >> 16) & 1u)) >> 16);
}

#define GLOBAL_LDS16(g, l)                                                     \
    __builtin_amdgcn_global_load_lds(                                          \
        (const __attribute__((address_space(1))) void*)(g),                    \
        (__attribute__((address_space(3))) void*)(l), 16, 0, 0)

// ---------------------------------------------------------------------------
// Prep: fused x-convert + 3 weight transposes (flat grid, uniform branch)
// ---------------------------------------------------------------------------
#define CVT_BLKS  (B_ * IN_ / 4 / 256)                       // 16384
#define WT1_TILES ((EH1_ / 32) * (IN_ / 32) * E_)            // 1536
#define WT2_TILES ((EH2_ / 32) * (EH1_ / 32) * E_)           // 192
#define WTG_TILES ((GH_ / 32) * (IN_ / 32) * D_)             // 1280
#define PREP_BLKS (CVT_BLKS + WT1_TILES + WT2_TILES + WTG_TILES)

__global__ __launch_bounds__(256) void k_prep(
        const float* __restrict__ x, ushort* __restrict__ xb,
        const float* __restrict__ Ew1, ushort* __restrict__ W1t,
        const float* __restrict__ Ew2, ushort* __restrict__ W2t,
        const float* __restrict__ Gw1, ushort* __restrict__ G1t) {
    __shared__ float tile[32][33];
    int bid = blockIdx.x;
    const int t = threadIdx.x;

    if (bid < CVT_BLKS) {
        int i = bid * 256 + t;
        float4 v = ((const float4*)x)[i];
        ushort4 o;
        o.x = f2bf(v.x); o.y = f2bf(v.y); o.z = f2bf(v.z); o.w = f2bf(v.w);
        ((ushort4*)xb)[i] = o;
        return;
    }
    bid -= CVT_BLKS;

    const float* W; ushort* Wt; int K, N, z, ky, nx;
    if (bid < WT1_TILES) {
        W = Ew1; Wt = W1t; K = IN_; N = EH1_;
        z = bid / (8 * 32); int r = bid % (8 * 32); ky = r / 8; nx = r % 8;
    } else if (bid < WT1_TILES + WT2_TILES) {
        bid -= WT1_TILES;
        W = Ew2; Wt = W2t; K = EH1_; N = EH2_;
        z = bid / (4 * 8); int r = bid % (4 * 8); ky = r / 4; nx = r % 4;
    } else {
        bid -= WT1_TILES + WT2_TILES;
        W = Gw1; Wt = G1t; K = IN_; N = GH_;
        z = bid / (2 * 32); int r = bid % (2 * 32); ky = r / 2; nx = r % 2;
    }
    const int n0 = nx * 32, k0 = ky * 32;
    const float* We = W + (size_t)z * K * N;
    ushort* Wte = Wt + (size_t)z * K * N;
    const int lx = t & 31, ly = t >> 5;
    #pragma unroll
    for (int r = 0; r < 4; ++r)
        tile[ly + r * 8][lx] = We[(size_t)(k0 + ly + r * 8) * N + n0 + lx];
    __syncthreads();
    #pragma unroll
    for (int r = 0; r < 4; ++r)
        Wte[(size_t)(n0 + ly + r * 8) * K + k0 + lx] = f2bf(tile[lx][ly + r * 8]);
}

// ---------------------------------------------------------------------------
// Fused histogram + prefix (single block, LDS atomics)
// ---------------------------------------------------------------------------
__global__ __launch_bounds__(256) void k_prefix2(
        const int* __restrict__ dom, int* __restrict__ hist,
        int* __restrict__ baseA, int* __restrict__ cursor) {
    __shared__ int h[D_];
    const int t = threadIdx.x;
    if (t < D_) h[t] = 0;
    __syncthreads();
    for (int i = t; i < B_; i += 256) atomicAdd(&h[dom[i]], 1);
    __syncthreads();
    if (t == 0) {
        int s = 0;
        for (int i = 0; i < D_; ++i) {
            baseA[i] = s; cursor[i] = s; hist[i] = h[i]; s += h[i];
        }
    }
}

__global__ void k_scatter(const int* __restrict__ dom, int* __restrict__ cursor,
                          int* __restrict__ perm) {
    int g = blockIdx.x * blockDim.x + threadIdx.x;
    if (g < B_) {
        int pos = atomicAdd(&cursor[dom[g]], 1);
        perm[pos] = g;
    }
}

#define GBK 32
#define H2P 136

// ---------------------------------------------------------------------------
// bf16 MFMA GEMM (R8, verified best: 73us): 32x32x16, 128x128 tile, BK=32,
// R5 staging (4 lanes cover one row's contiguous 64B) + XOR swizzle.
// A-frag: m=lane&31, k=(lane>>5)*8+j.  C/D: col=lane&31,
// row=(reg&3)+8*(reg>>2)+4*(lane>>5)  [HW-verified m74/m101].
// NOTE (R9/R10 lessons): do NOT perturb the staging mapping (chunk-major
// broke global coalescing: FETCH 72->162MB) and do NOT grow the acc to 128
// VGPRs / 256-row tile (occupancy+L2-reuse collapse: 121us).
// ---------------------------------------------------------------------------
__global__ __launch_bounds__(256) void k_mfma_gemm(
        const ushort* __restrict__ A, size_t aStride,
        const ushort* __restrict__ Wt, const float* __restrict__ Bias,
        ushort* __restrict__ C, int M, int N, int K, int eBase) {
    __shared__ __attribute__((aligned(16))) ushort As[128 * GBK];
    __shared__ __attribute__((aligned(16))) ushort Bs[128 * GBK];

    const int z = blockIdx.z;
    const int eAbs = eBase + z;
    const ushort* Ae = A + (size_t)z * aStride;
    const ushort* We = Wt + (size_t)eAbs * (size_t)N * K;
    const float* BiasE = Bias + (size_t)eAbs * N;
    ushort* Ce = C + (size_t)z * (size_t)M * N;

    const int m0 = blockIdx.y * 128;
    const int n0 = blockIdx.x * 128;
    const int t = threadIdx.x;
    const int wave = t >> 6;
    const int lane = t & 63;

    const int q0 = wave * 2, q1 = q0 + 1;
    const int sr0 = q0 * 16 + (lane >> 2);
    const int sr1 = sr0 + 16;                       // (sr1>>1)&3 == (sr0>>1)&3
    const int sw  = ((lane & 3) ^ ((sr0 >> 1) & 3)) * 8;

    const int l32  = lane & 31;
    const int ksel = lane >> 5;
    const int rw = (wave & 1) * 64;
    const int cw = (wave >> 1) * 64;

    int rowA[2], rowB[2], swzA[2], swzB[2];
    #pragma unroll
    for (int i = 0; i < 2; ++i) {
        rowA[i] = rw + 32 * i + l32;  swzA[i] = (rowA[i] >> 1) & 3;
        rowB[i] = cw + 32 * i + l32;  swzB[i] = (rowB[i] >> 1) & 3;
    }

    f32x16 acc[2][2] = {};

    for (int k0 = 0; k0 < K; k0 += GBK) {
        GLOBAL_LDS16(Ae + (size_t)(m0 + sr0) * K + k0 + sw, As + q0 * 512);
        GLOBAL_LDS16(Ae + (size_t)(m0 + sr1) * K + k0 + sw, As + q1 * 512);
        GLOBAL_LDS16(We + (size_t)(n0 + sr0) * K + k0 + sw, Bs + q0 * 512);
        GLOBAL_LDS16(We + (size_t)(n0 + sr1) * K + k0 + sw, Bs + q1 * 512);
        __syncthreads();

        #pragma unroll
        for (int h = 0; h < 2; ++h) {           // two K=16 halves per window
            const int cb = h * 2 + ksel;
            s16x8 af[2], bf[2];
            #pragma unroll
            for (int i = 0; i < 2; ++i)
                af[i] = *(const s16x8*)&As[rowA[i] * GBK + ((cb ^ swzA[i]) * 8)];
            #pragma unroll
            for (int j = 0; j < 2; ++j)
                bf[j] = *(const s16x8*)&Bs[rowB[j] * GBK + ((cb ^ swzB[j]) * 8)];
            #pragma unroll
            for (int i = 0; i < 2; ++i)
                #pragma unroll
                for (int j = 0; j < 2; ++j)
                    acc[i][j] = __builtin_amdgcn_mfma_f32_32x32x16_bf16(
                        af[i], bf[j], acc[i][j], 0, 0, 0);
        }
        __syncthreads();
    }

    float bi[2];
    #pragma unroll
    for (int j = 0; j < 2; ++j) bi[j] = BiasE[n0 + cw + 32 * j + l32];

    #pragma unroll
    for (int i = 0; i < 2; ++i) {
        #pragma unroll
        for (int reg = 0; reg < 16; ++reg) {
            int rowin = (reg & 3) + 8 * (reg >> 2) + 4 * ksel;
            ushort* crow = Ce + (size_t)(m0 + rw + 32 * i + rowin) * N;
            #pragma unroll
            for (int j = 0; j < 2; ++j) {
                float v = fmaxf(acc[i][j][reg] + bi[j], 0.f);
                crow[n0 + cw + 32 * j + l32] = f2bf(v);
            }
        }
    }
}

// ---------------------------------------------------------------------------
// Fused expert L2+L3, main loop upgraded to 32x32x16 (R8-verified path):
// h2 = relu(h1 . W2^T + Eb2), then eo = h2 . Ew3 + Eb3 in-block.
// Staging + phase-B unchanged from R5 (verified). Only fragment reads, MFMA
// shape, and the h2->LDS scatter mapping change.
// ---------------------------------------------------------------------------
__global__ __launch_bounds__(256) void k_l2eo(
        const ushort* __restrict__ h1, const ushort* __restrict__ W2t,
        const float* __restrict__ Eb2, const float* __restrict__ Ew3,
        const float* __restrict__ Eb3, float* __restrict__ eo, int eBase) {
    __shared__ __attribute__((aligned(16))) ushort smem[17408 + 16 * H2P];
    ushort* As = smem;            // 128*32 elems (main loop)
    ushort* Bs = smem + 4096;     // 128*32 elems (main loop)

    const int z = blockIdx.y;
    const int eAbs = eBase + z;
    const ushort* Ae = h1 + (size_t)z * B_ * EH1_;
    const ushort* We = W2t + (size_t)eAbs * EH2_ * EH1_;   // [N=128][K=256]

    const int m0 = blockIdx.x * 128;
    const int t = threadIdx.x;
    const int wave = t >> 6;
    const int lane = t & 63;

    const int q0 = wave * 2, q1 = q0 + 1;
    const int sr0 = q0 * 16 + (lane >> 2);
    const int sr1 = sr0 + 16;
    const int sw  = ((lane & 3) ^ ((sr0 >> 1) & 3)) * 8;

    const int quad = lane >> 4;
    const int l16  = lane & 15;
    const int l32  = lane & 31;
    const int ksel = lane >> 5;
    const int rw = (wave & 1) * 64;
    const int cw = (wave >> 1) * 64;

    int rowA[2], rowB[2], swzA[2], swzB[2];
    #pragma unroll
    for (int i = 0; i < 2; ++i) {
        rowA[i] = rw + 32 * i + l32;  swzA[i] = (rowA[i] >> 1) & 3;
        rowB[i] = cw + 32 * i + l32;  swzB[i] = (rowB[i] >> 1) & 3;
    }

    f32x16 acc[2][2] = {};

    for (int k0 = 0; k0 < EH1_; k0 += GBK) {
        GLOBAL_LDS16(Ae + (size_t)(m0 + sr0) * EH1_ + k0 + sw, As + q0 * 512);
        GLOBAL_LDS16(Ae + (size_t)(m0 + sr1) * EH1_ + k0 + sw, As + q1 * 512);
        GLOBAL_LDS16(We + (size_t)sr0 * EH1_ + k0 + sw, Bs + q0 * 512);
        GLOBAL_LDS16(We + (size_t)sr1 * EH1_ + k0 + sw, Bs + q1 * 512);
        __syncthreads();

        #pragma unroll
        for (int h = 0; h < 2; ++h) {
            const int cb = h * 2 + ksel;
            s16x8 af[2], bf[2];
            #pragma unroll
            for (int i = 0; i < 2; ++i)
                af[i] = *(const s16x8*)&As[rowA[i] * GBK + ((cb ^ swzA[i]) * 8)];
            #pragma unroll
            for (int j = 0; j < 2; ++j)
                bf[j] = *(const s16x8*)&Bs[rowB[j] * GBK + ((cb ^ swzB[j]) * 8)];
            #pragma unroll
            for (int i = 0; i < 2; ++i)
                #pragma unroll
                for (int j = 0; j < 2; ++j)
                    acc[i][j] = __builtin_amdgcn_mfma_f32_32x32x16_bf16(
                        af[i], bf[j], acc[i][j], 0, 0, 0);
        }
        __syncthreads();
    }

    // epilogue: h2 tile (bias+relu, bf16) -> LDS, 32x32 C/D scatter
    ushort* h2L = smem;             // [128][H2P]
    ushort* E3t = smem + 128 * H2P; // [16][H2P]  (cols >= EO_ zero)

    float bi[2];
    #pragma unroll
    for (int j = 0; j < 2; ++j) bi[j] = Eb2[eAbs * EH2_ + cw + 32 * j + l32];

    #pragma unroll
    for (int i = 0; i < 2; ++i)
        #pragma unroll
        for (int reg = 0; reg < 16; ++reg) {
            int rowin = (reg & 3) + 8 * (reg >> 2) + 4 * ksel;
            int row = rw + 32 * i + rowin;
            #pragma unroll
            for (int j = 0; j < 2; ++j)
                h2L[row * H2P + cw + 32 * j + l32] =
                    f2bf(fmaxf(acc[i][j][reg] + bi[j], 0.f));
        }

    for (int i = t; i < 16 * 128; i += 256) {
        int col = i >> 7, k = i & 127;
        float v = (col < EO_) ? Ew3[(size_t)eAbs * EH2_ * EO_ + k * EO_ + col] : 0.f;
        E3t[col * H2P + k] = f2bf(v);
    }
    __syncthreads();

    // phase B (unchanged, 16x16x32): eo = h2 . Ew3 + b3
    #pragma unroll
    for (int gi = 0; gi < 2; ++gi) {
        int g = wave * 2 + gi;
        f32x4 acc2 = {};
        #pragma unroll
        for (int kc = 0; kc < 4; ++kc) {
            s16x8 a = *(const s16x8*)&h2L[(g * 16 + l16) * H2P + kc * 32 + quad * 8];
            s16x8 b = *(const s16x8*)&E3t[l16 * H2P + kc * 32 + quad * 8];
            acc2 = __builtin_amdgcn_mfma_f32_16x16x32_bf16(a, b, acc2, 0, 0, 0);
        }
        if (l16 < EO_) {
            float b3 = Eb3[eAbs * EO_ + l16];
            #pragma unroll
            for (int r = 0; r < 4; ++r) {
                int row = m0 + g * 16 + quad * 4 + r;
                eo[(size_t)row * (E_ * EO_) + eAbs * EO_ + l16] = acc2[r] + b3;
            }
        }
    }
}

// ---------------------------------------------------------------------------
// Gate (MFMA, fused): per (domain, 64-row tile) block, with bank swizzle.
// ---------------------------------------------------------------------------
__global__ __launch_bounds__(256) void k_gate2(
        const ushort* __restrict__ xb, const ushort* __restrict__ Gw1t,
        const float* __restrict__ Gb1, const float* __restrict__ Gw2,
        const float* __restrict__ Gb2, const int* __restrict__ perm,
        const int* __restrict__ baseA, const int* __restrict__ cntA,
        float* __restrict__ gate) {
    const int d = blockIdx.y;
    const int cnt = cntA[d];
    const int start = blockIdx.x * 64;
    if (start >= cnt) return;
    const int base = baseA[d];

    __shared__ __attribute__((aligned(16))) ushort As[64 * 32];
    __shared__ __attribute__((aligned(16))) ushort Bs[64 * 32];
    __shared__ int    ridx[64];
    __shared__ float  gh[64][GH_ + 1];
    __shared__ float  w2s[GH_ * E_];
    __shared__ float  b2s[E_];
    __shared__ float  lg[64][E_];

    const int t = threadIdx.x;
    const int wave = t >> 6;
    const int lane = t & 63;
    const int quad = lane >> 4;
    const int l16  = lane & 15;
    const int qsw  = (quad ^ ((l16 >> 1) & 3)) * 8;

    if (t < 64) {
        int p = start + t;
        ridx[t] = (p < cnt) ? perm[base + p] : perm[base];  // clamp OOB
    }
    for (int i = t; i < GH_ * E_; i += 256) w2s[i] = Gw2[(size_t)d * GH_ * E_ + i];
    if (t < E_) b2s[t] = Gb2[d * E_ + t];
    __syncthreads();

    const int srow = t >> 2;
    const int sw   = ((t & 3) ^ ((srow >> 1) & 3)) * 8;
    const int myRow = ridx[srow];
    const ushort* aRow = xb + (size_t)myRow * IN_ + sw;
    const ushort* bRow = Gw1t + (size_t)d * GH_ * IN_ + (size_t)srow * IN_ + sw;

    f32x4 acc[4] = {};
    for (int k0 = 0; k0 < IN_; k0 += 32) {
        GLOBAL_LDS16(aRow + k0, As + wave * 512);
        GLOBAL_LDS16(bRow + k0, Bs + wave * 512);
        __syncthreads();

        s16x8 bf = *(const s16x8*)&Bs[(wave * 16 + l16) * 32 + qsw];
        #pragma unroll
        for (int i = 0; i < 4; ++i) {
            s16x8 af = *(const s16x8*)&As[(16 * i + l16) * 32 + qsw];
            acc[i] = __builtin_amdgcn_mfma_f32_16x16x32_bf16(af, bf, acc[i], 0, 0, 0);
        }
        __syncthreads();
    }

    const int hcol = wave * 16 + l16;
    float hb = Gb1[d * GH_ + hcol];
    #pragma unroll
    for (int i = 0; i < 4; ++i)
        #pragma unroll
        for (int r = 0; r < 4; ++r)
            gh[16 * i + quad * 4 + r][hcol] = fmaxf(acc[i][r] + hb, 0.f);
    __syncthreads();

    // layer 2: 64 rows x 6 experts = 384 pairs, strided over 256 threads
    for (int p = t; p < 64 * E_; p += 256) {
        int row = p / E_, e = p - row * E_;
        float s = b2s[e];
        #pragma unroll 8
        for (int h = 0; h < GH_; ++h) s += gh[row][h] * w2s[h * E_ + e];
        lg[row][e] = s;
    }
    __syncthreads();

    if (t < 64 && start + t < cnt) {
        int b = ridx[t];
        float mx = lg[t][0];
        #pragma unroll
        for (int e = 1; e < E_; ++e) mx = fmaxf(mx, lg[t][e]);
        float ex[E_], sum = 0.f;
        #pragma unroll
        for (int e = 0; e < E_; ++e) { ex[e] = expf(lg[t][e] - mx); sum += ex[e]; }
        float inv = 1.f / sum;
        #pragma unroll
        for (int e = 0; e < E_; ++e) gate[(size_t)b * E_ + e] = ex[e] * inv;
    }
}

// ---------------------------------------------------------------------------
// Final: MMoE combine + avg + tower, one wave per sample
// ---------------------------------------------------------------------------
__global__ __launch_bounds__(256) void k_final(
        const float* __restrict__ eo, const float* __restrict__ gate,
        const int* __restrict__ dom,
        const float* __restrict__ Tw1, const float* __restrict__ Tb1,
        const float* __restrict__ Tw2, const float* __restrict__ Tb2,
        float* __restrict__ out) {
    const int wave = threadIdx.x >> 6;
    const int lane = threadIdx.x & 63;
    const int b = blockIdx.x * 4 + wave;
    const int d = dom[b];

    const float* eob = eo + (size_t)b * (E_ * EO_);
    float g[E_];
    #pragma unroll
    for (int e = 0; e < E_; ++e) g[e] = gate[(size_t)b * E_ + e];

    float mmoe[EO_], avg[EO_];
    #pragma unroll
    for (int o = 0; o < EO_; ++o) {
        float m = 0.f, a = 0.f;
        #pragma unroll
        for (int e = 0; e < E_; ++e) {
            float v = eob[e * EO_ + o];
            m += g[e] * v;
            a += v;
        }
        mmoe[o] = m;
        avg[o] = a * (1.0f / E_);
    }

    float acc = Tb1[d * TH_ + lane];
    #pragma unroll
    for (int o = 0; o < EO_; ++o)
        acc += mmoe[o] * Tw1[(size_t)d * EO_ * TH_ + o * TH_ + lane];
    acc = fmaxf(acc, 0.f);

    float s = acc * Tw2[d * TH_ + lane];
    #pragma unroll
    for (int off = 32; off >= 1; off >>= 1) s += __shfl_xor(s, off, 64);

    if (lane == 0)
        out[b] = 1.f / (1.f + expf(-(s + Tb2[d])));
    if (lane < EO_) {
        out[B_ + (size_t)b * EO_ + lane] = avg[lane];
        out[B_ + (size_t)B_ * EO_ + (size_t)b * EO_ + lane] = mmoe[lane];
    }
}

// ---------------------------------------------------------------------------
extern "C" void kernel_launch(void* const* d_in, const int* in_sizes, int n_in,
                              void* d_out, int out_size, void* d_ws, size_t ws_size,
                              hipStream_t stream) {
    const float* x   = (const float*)d_in[0];
    const int*   dom = (const int*)d_in[1];
    const float* Ew1 = (const float*)d_in[2];
    const float* Eb1 = (const float*)d_in[3];
    const float* Ew2 = (const float*)d_in[4];
    const float* Eb2 = (const float*)d_in[5];
    const float* Ew3 = (const float*)d_in[6];
    const float* Eb3 = (const float*)d_in[7];
    const float* Gw1 = (const float*)d_in[8];
    const float* Gb1 = (const float*)d_in[9];
    const float* Gw2 = (const float*)d_in[10];
    const float* Gb2 = (const float*)d_in[11];
    const float* Tw1 = (const float*)d_in[12];
    const float* Tb1 = (const float*)d_in[13];
    const float* Tw2 = (const float*)d_in[14];
    const float* Tb2 = (const float*)d_in[15];
    float* out = (float*)d_out;

    char* ws = (char*)d_ws;
    size_t off = 0;
    auto take = [&](size_t bytes) -> char* {
        char* p = ws + off;
        off = (off + bytes + 255) & ~(size_t)255;
        return p;
    };
    int*    hist    = (int*)take(D_ * 4);
    int*    baseA   = (int*)take(D_ * 4);
    int*    cursor  = (int*)take(D_ * 4);
    int*    perm    = (int*)take(B_ * 4);
    float*  gateBuf = (float*)take((size_t)B_ * E_ * 4);
    float*  eoBuf   = (float*)take((size_t)B_ * E_ * EO_ * 4);
    ushort* xb      = (ushort*)take((size_t)B_ * IN_ * 2);
    ushort* W1t     = (ushort*)take((size_t)E_ * IN_ * EH1_ * 2);
    ushort* W2t     = (ushort*)take((size_t)E_ * EH1_ * EH2_ * 2);
    ushort* G1t     = (ushort*)take((size_t)D_ * IN_ * GH_ * 2);
    size_t fixed = off;

    int G = 1;
    const int cands[4] = {6, 3, 2, 1};
    for (int ci = 0; ci < 4; ++ci) {
        size_t need = fixed + (size_t)cands[ci] * B_ * EH1_ * 2 + 1024;
        if (need <= ws_size) { G = cands[ci]; break; }
    }
    ushort* h1 = (ushort*)take((size_t)G * B_ * EH1_ * 2);

    // fused conversions (cvt + all weight transposes)
    k_prep<<<dim3(PREP_BLKS), dim3(256), 0, stream>>>(
        x, xb, Ew1, W1t, Ew2, W2t, Gw1, G1t);

    // domain bucketing (hist+prefix fused, then scatter)
    k_prefix2<<<dim3(1), dim3(256), 0, stream>>>(dom, hist, baseA, cursor);
    k_scatter<<<dim3(B_ / 256), dim3(256), 0, stream>>>(dom, cursor, perm);

    // gates (selected domain only, MFMA + fused softmax)
    k_gate2<<<dim3((B_ + 63) / 64, D_), dim3(256), 0, stream>>>(
        xb, G1t, Gb1, Gw2, Gb2, perm, baseA, hist, gateBuf);

    // experts: L1 MFMA gemm (R8 config), then fused L2+L3 (32x32 main loop)
    for (int g0 = 0; g0 < E_; g0 += G) {
        k_mfma_gemm<<<dim3(EH1_ / 128, B_ / 128, G), dim3(256), 0, stream>>>(
            xb, (size_t)0, W1t, Eb1, h1, B_, EH1_, IN_, g0);
        k_l2eo<<<dim3(B_ / 128, G), dim3(256), 0, stream>>>(
            h1, W2t, Eb2, Ew3, Eb3, eoBuf, g0);
    }

    // combine + towers + outputs
    k_final<<<dim3(B_ / 4), dim3(256), 0, stream>>>(
        eoBuf, gateBuf, dom, Tw1, Tb1, Tw2, Tb2, out);
}